// Round 4
// baseline (2810.217 us; speedup 1.0000x reference)
//
#include <hip/hip_runtime.h>
#include <hip/hip_bf16.h>

#define BK   128      // nodes per bucket
#define NBMAX 2048    // max buckets (N<=262144)

// ---------------- CSR-free bucket build ----------------

// count edges per bucket (bucket = dst >> 7)
__global__ void __launch_bounds__(256) k_bcount(const int* dst, int* bcnt, int E, int NB) {
    __shared__ int h[NBMAX];
    for (int i = threadIdx.x; i < NB; i += 256) h[i] = 0;
    __syncthreads();
    int stride = gridDim.x * 256;
    for (int e = blockIdx.x * 256 + threadIdx.x; e < E; e += stride)
        atomicAdd(&h[dst[e] >> 7], 1);
    __syncthreads();
    for (int i = threadIdx.x; i < NB; i += 256) {
        int v = h[i];
        if (v) atomicAdd(&bcnt[i], v);
    }
}

// exclusive scan of bucket counts (single block)
__global__ void __launch_bounds__(256) k_bscan(const int* bcnt, int* boff, int* bcur, int NB, int E) {
    __shared__ int lds[256];
    __shared__ int carry;
    int t = threadIdx.x;
    if (t == 0) carry = 0;
    __syncthreads();
    for (int base = 0; base < NB; base += 256) {
        int v = (base + t < NB) ? bcnt[base + t] : 0;
        lds[t] = v;
        __syncthreads();
        for (int o = 1; o < 256; o <<= 1) {
            int u = (t >= o) ? lds[t - o] : 0;
            __syncthreads();
            lds[t] += u;
            __syncthreads();
        }
        int excl = lds[t] - v + carry;
        if (base + t < NB) { boff[base + t] = excl; bcur[base + t] = excl; }
        __syncthreads();
        if (t == 0) carry += lds[255];
        __syncthreads();
    }
    if (t == 0) boff[NB] = E;
}

// scatter packed (src<<7 | dst&127) into bucket-grouped staging.
// Each block: LDS hist -> reserve contiguous runs -> write (runs ~10 entries).
#define EPB 16384
__global__ void __launch_bounds__(256) k_bscatter(const int* ei, int* bcur,
                                                  unsigned* stag, int E, int NB) {
    __shared__ int lhist[NBMAX];
    __shared__ int lbase[NBMAX];
    int t = threadIdx.x;
    for (int i = t; i < NB; i += 256) lhist[i] = 0;
    __syncthreads();
    int base = blockIdx.x * EPB;
    int lim = min(EPB, E - base);
    for (int c = t; c < lim; c += 256)
        atomicAdd(&lhist[ei[E + base + c] >> 7], 1);
    __syncthreads();
    for (int i = t; i < NB; i += 256) {
        int v = lhist[i];
        lbase[i] = v ? atomicAdd(&bcur[i], v) : 0;
    }
    __syncthreads();
    for (int c = t; c < lim; c += 256) {
        int s = ei[base + c];
        int d = ei[E + base + c];
        int p = atomicAdd(&lbase[d >> 7], 1);
        stag[p] = ((unsigned)s << 7) | (unsigned)(d & (BK - 1));
    }
}

// per-bucket degree count -> dis = rsqrt(deg+1), dx = dis*x
__global__ void __launch_bounds__(256) k_bdeg(const int* boff, const unsigned* stag,
                                              const float* x, float* dis, float* dx, int N) {
    __shared__ int cnt[BK];
    int t = threadIdx.x, bu = blockIdx.x;
    if (t < BK) cnt[t] = 0;
    __syncthreads();
    int lo = boff[bu], hi = boff[bu + 1];
    for (int k = lo + t; k < hi; k += 256)
        atomicAdd(&cnt[stag[k] & (BK - 1)], 1);
    __syncthreads();
    int node = bu * BK + t;
    if (t < BK && node < N) {
        float d = rsqrtf((float)(cnt[t] + 1));   // +1 self-loop
        dis[node] = d;
        dx[node]  = d * x[node];
    }
}

// layer-1 scalar aggregation via LDS accumulators (self-loop analytic)
__global__ void __launch_bounds__(256) k_bagg1(const int* boff, const unsigned* stag,
                                               const float* dx, const float* dis,
                                               float* s1, int N) {
    __shared__ float acc[BK];
    int t = threadIdx.x, bu = blockIdx.x;
    if (t < BK) acc[t] = 0.f;
    __syncthreads();
    int lo = boff[bu], hi = boff[bu + 1];
    for (int k = lo + t; k < hi; k += 256) {
        unsigned en = stag[k];
        atomicAdd(&acc[en & (BK - 1)], dx[en >> 7]);
    }
    __syncthreads();
    int node = bu * BK + t;
    if (t < BK && node < N)
        s1[node] = dis[node] * (acc[t] + dx[node]);
}

// hw1b[i] = bf16( dis[i] * (relu(s1[i]*Wg1 + bg1) @ Wg2) ), Wg2 in LDS
__global__ void __launch_bounds__(256) k_hw1(const float* s1, const float* dis,
                                             const float* Wg1, const float* bg1,
                                             const float* Wg2,
                                             __hip_bfloat16* hw1b, int N) {
    __shared__ float w2[64 * 64];
    __shared__ float h1l[4][64];
    int t = threadIdx.x;
    for (int k = t; k < 64 * 64; k += 256) w2[k] = Wg2[k];
    int nl = t >> 6, l = t & 63;
    int base = blockIdx.x * 16;
    for (int g = 0; g < 4; ++g) {
        int node = base + g * 4 + nl;
        float h1 = 0.f;
        if (node < N)
            h1 = fmaxf(fmaf(s1[node], Wg1[l], bg1[l]), 0.f);
        __syncthreads();
        h1l[nl][l] = h1;
        __syncthreads();
        if (node < N) {
            float acc = 0.f;
            const float* hr = h1l[nl];
            #pragma unroll
            for (int k = 0; k < 64; ++k) acc += hr[k] * w2[k * 64 + l];
            hw1b[node * 64 + l] = __float2bfloat16(dis[node] * acc);
        }
    }
}

// layer-2 aggregation: bucket per block, 128x64 f32 LDS accumulator.
// Wave per edge (lane = feature), then fused relu + per-graph pooling.
__global__ void __launch_bounds__(256) k_bagg2(const int* boff, const unsigned* stag,
                                               const __hip_bfloat16* hw1b,
                                               const float* dis, const float* bg2,
                                               const int* batch, float* pool, int N) {
    __shared__ float acc[BK * 64];     // 32 KB
    __shared__ unsigned ent[1024];     // 4 KB entry staging
    int t = threadIdx.x, bu = blockIdx.x;
    int l = t & 63, w = t >> 6;
    for (int i = t; i < BK * 64; i += 256) acc[i] = 0.f;
    int lo = boff[bu], hi = boff[bu + 1];
    __syncthreads();
    for (int cb = lo; cb < hi; cb += 1024) {
        int cnt = min(1024, hi - cb);
        for (int i = t; i < cnt; i += 256) ent[i] = stag[cb + i];
        __syncthreads();
        int per = (cnt + 3) >> 2;
        int wb = w * per, we = min(wb + per, cnt);
        for (int k = wb; k < we; ++k) {
            unsigned en = ent[k];
            int src = en >> 7;
            int dl2 = en & (BK - 1);
            float v = __bfloat162float(hw1b[src * 64 + l]);
            atomicAdd(&acc[dl2 * 64 + l], v);
        }
        __syncthreads();
    }
    // finalize: self-loop + relu + segmented (sorted batch) pooling, wave 0 only
    if (w == 0) {
        int nmax = min(BK, N - bu * BK);
        float b2 = bg2[l];
        float pacc = 0.f;
        int gprev = -1;
        for (int n = 0; n < nmax; ++n) {
            int node = bu * BK + n;
            float tot = acc[n * 64 + l] + __bfloat162float(hw1b[node * 64 + l]);
            float h2 = fmaxf(fmaf(dis[node], tot, b2), 0.f);
            int g = batch[node];
            if (g != gprev) {
                if (gprev >= 0) atomicAdd(&pool[gprev * 64 + l], pacc);
                pacc = 0.f;
                gprev = g;
            }
            pacc += h2;
        }
        if (gprev >= 0) atomicAdd(&pool[gprev * 64 + l], pacc);
    }
}

// per-graph head: tabular MLP + mean pool + fusion MLP. 64 threads per graph.
__global__ void __launch_bounds__(64) k_head(const float* tabular,
        const float* Wt1, const float* bt1, const float* Wt2, const float* bt2,
        const float* Wf1, const float* bf1, const float* Wf2, const float* bf2,
        const float* pool, const int* batch, float* out, int TD, int N) {
    __shared__ float tl[128];
    __shared__ float t1[64];
    __shared__ float comb[128];
    __shared__ float f1[64];
    __shared__ float cnts;
    int g = blockIdx.x, l = threadIdx.x;
    if (l == 0) {
        int lo = 0, hi = N;
        while (lo < hi) { int m = (lo + hi) >> 1; if (batch[m] < g) lo = m + 1; else hi = m; }
        int lo2 = lo, hi2 = N;
        while (lo2 < hi2) { int m = (lo2 + hi2) >> 1; if (batch[m] <= g) lo2 = m + 1; else hi2 = m; }
        int c = lo2 - lo;
        cnts = (float)(c > 1 ? c : 1);
    }
    for (int k = l; k < TD; k += 64) tl[k] = tabular[g * TD + k];
    __syncthreads();
    float a = bt1[l];
    for (int k = 0; k < TD; ++k) a += tl[k] * Wt1[k * 64 + l];
    t1[l] = a > 0.f ? a : 0.f;
    __syncthreads();
    float b = bt2[l];
    #pragma unroll
    for (int k = 0; k < 64; ++k) b += t1[k] * Wt2[k * 64 + l];
    comb[l] = b;
    comb[64 + l] = pool[g * 64 + l] / cnts;
    __syncthreads();
    float f = bf1[l];
    for (int k = 0; k < 128; ++k) f += comb[k] * Wf1[k * 64 + l];
    f1[l] = f > 0.f ? f : 0.f;
    __syncthreads();
    if (l < 2) {
        float o = bf2[l];
        #pragma unroll
        for (int k = 0; k < 64; ++k) o += f1[k] * Wf2[k * 2 + l];
        out[g * 2 + l] = o;
    }
}

// ---------------- launcher ----------------

extern "C" void kernel_launch(void* const* d_in, const int* in_sizes, int n_in,
                              void* d_out, int out_size, void* d_ws, size_t ws_size,
                              hipStream_t stream) {
    const float* tabular = (const float*)d_in[0];
    const float* x       = (const float*)d_in[1];
    const int*   ei      = (const int*)d_in[2];
    const int*   batch   = (const int*)d_in[3];
    const float* Wt1 = (const float*)d_in[4];
    const float* bt1 = (const float*)d_in[5];
    const float* Wt2 = (const float*)d_in[6];
    const float* bt2 = (const float*)d_in[7];
    const float* Wg1 = (const float*)d_in[8];
    const float* bg1 = (const float*)d_in[9];
    const float* Wg2 = (const float*)d_in[10];
    const float* bg2 = (const float*)d_in[11];
    const float* Wf1 = (const float*)d_in[12];
    const float* bf1 = (const float*)d_in[13];
    const float* Wf2 = (const float*)d_in[14];
    const float* bf2 = (const float*)d_in[15];

    const int N  = in_sizes[1];
    const int E  = in_sizes[2] / 2;
    const int H  = in_sizes[5];             // 64
    const int TD = in_sizes[4] / H;         // 128
    const int B  = in_sizes[0] / TD;        // 1024
    const int NB = (N + BK - 1) / BK;       // 1563

    // workspace layout
    char* w = (char*)d_ws;
    size_t off = 0;
    auto alloc = [&](size_t bytes) -> void* {
        void* p = w + off;
        off = (off + bytes + 255) & ~(size_t)255;
        return p;
    };
    int*   bcnt = (int*)alloc((size_t)NBMAX * 4);
    int*   boff = (int*)alloc((size_t)(NBMAX + 1) * 4);
    int*   bcur = (int*)alloc((size_t)NBMAX * 4);
    float* dis  = (float*)alloc((size_t)N * 4);
    float* dx   = (float*)alloc((size_t)N * 4);
    float* s1   = (float*)alloc((size_t)N * 4);
    unsigned* stag = (unsigned*)alloc((size_t)E * 4);
    __hip_bfloat16* hw1b = (__hip_bfloat16*)alloc((size_t)N * 64 * 2);
    float* pool = (float*)alloc((size_t)B * 64 * 4);
    (void)ws_size;

    hipMemsetAsync(bcnt, 0, (size_t)NB * 4, stream);
    hipMemsetAsync(pool, 0, (size_t)B * 64 * 4, stream);

    k_bcount<<<512, 256, 0, stream>>>(ei + E, bcnt, E, NB);
    k_bscan<<<1, 256, 0, stream>>>(bcnt, boff, bcur, NB, E);
    k_bscatter<<<(E + EPB - 1) / EPB, 256, 0, stream>>>(ei, bcur, stag, E, NB);
    k_bdeg<<<NB, 256, 0, stream>>>(boff, stag, x, dis, dx, N);
    k_bagg1<<<NB, 256, 0, stream>>>(boff, stag, dx, dis, s1, N);
    k_hw1<<<(N + 15) / 16, 256, 0, stream>>>(s1, dis, Wg1, bg1, Wg2, hw1b, N);
    k_bagg2<<<NB, 256, 0, stream>>>(boff, stag, hw1b, dis, bg2, batch, pool, N);
    k_head<<<B, 64, 0, stream>>>(tabular, Wt1, bt1, Wt2, bt2,
                                 Wf1, bf1, Wf2, bf2, pool, batch,
                                 (float*)d_out, TD, N);
}

// Round 5
// 621.840 us; speedup vs baseline: 4.5192x; 4.5192x over previous
//
#include <hip/hip_runtime.h>
#include <hip/hip_bf16.h>

#define BK   128      // nodes per bucket
#define NBMAX 2048    // max buckets (N<=262144)

// ---------------- bucket-grouped edge staging ----------------

// count edges per bucket (bucket = dst >> 7)
__global__ void __launch_bounds__(256) k_bcount(const int* dst, int* bcnt, int E, int NB) {
    __shared__ int h[NBMAX];
    for (int i = threadIdx.x; i < NB; i += 256) h[i] = 0;
    __syncthreads();
    int stride = gridDim.x * 256;
    for (int e = blockIdx.x * 256 + threadIdx.x; e < E; e += stride)
        atomicAdd(&h[dst[e] >> 7], 1);
    __syncthreads();
    for (int i = threadIdx.x; i < NB; i += 256) {
        int v = h[i];
        if (v) atomicAdd(&bcnt[i], v);
    }
}

// exclusive scan of bucket counts (single block)
__global__ void __launch_bounds__(256) k_bscan(const int* bcnt, int* boff, int* bcur, int NB, int E) {
    __shared__ int lds[256];
    __shared__ int carry;
    int t = threadIdx.x;
    if (t == 0) carry = 0;
    __syncthreads();
    for (int base = 0; base < NB; base += 256) {
        int v = (base + t < NB) ? bcnt[base + t] : 0;
        lds[t] = v;
        __syncthreads();
        for (int o = 1; o < 256; o <<= 1) {
            int u = (t >= o) ? lds[t - o] : 0;
            __syncthreads();
            lds[t] += u;
            __syncthreads();
        }
        int excl = lds[t] - v + carry;
        if (base + t < NB) { boff[base + t] = excl; bcur[base + t] = excl; }
        __syncthreads();
        if (t == 0) carry += lds[255];
        __syncthreads();
    }
    if (t == 0) boff[NB] = E;
}

// scatter packed (src<<7 | dst&127) into bucket-grouped staging.
#define EPB 16384
__global__ void __launch_bounds__(256) k_bscatter(const int* ei, int* bcur,
                                                  unsigned* stag, int E, int NB) {
    __shared__ int lhist[NBMAX];
    __shared__ int lbase[NBMAX];
    int t = threadIdx.x;
    for (int i = t; i < NB; i += 256) lhist[i] = 0;
    __syncthreads();
    int base = blockIdx.x * EPB;
    int lim = min(EPB, E - base);
    for (int c = t; c < lim; c += 256)
        atomicAdd(&lhist[ei[E + base + c] >> 7], 1);
    __syncthreads();
    for (int i = t; i < NB; i += 256) {
        int v = lhist[i];
        lbase[i] = v ? atomicAdd(&bcur[i], v) : 0;
    }
    __syncthreads();
    for (int c = t; c < lim; c += 256) {
        int s = ei[base + c];
        int d = ei[E + base + c];
        int p = atomicAdd(&lbase[d >> 7], 1);
        stag[p] = ((unsigned)s << 7) | (unsigned)(d & (BK - 1));
    }
}

// per-bucket counting sort: stag (bucket-grouped) -> csr (node-grouped).
// Also emits per-node offs, dis, dx. Writes land in the bucket's own
// 16KB window -> L2-resident, drains as full lines (no write amplification).
__global__ void __launch_bounds__(256) k_sort(const int* boff, const unsigned* stag,
                                              const float* x, int* csr, int* offs,
                                              float* dis, float* dx, int N, int NB) {
    __shared__ int cnt[BK];
    __shared__ int sc[BK];
    __shared__ int base[BK];
    int t = threadIdx.x, bu = blockIdx.x;
    if (t < BK) cnt[t] = 0;
    __syncthreads();
    int lo = boff[bu], hi = boff[bu + 1];
    for (int k = lo + t; k < hi; k += 256)
        atomicAdd(&cnt[stag[k] & (BK - 1)], 1);
    __syncthreads();
    if (t < BK) sc[t] = cnt[t];
    __syncthreads();
    for (int o = 1; o < BK; o <<= 1) {
        int v = (t < BK && t >= o) ? sc[t - o] : 0;
        __syncthreads();
        if (t < BK) sc[t] += v;
        __syncthreads();
    }
    int excl = (t < BK) ? sc[t] - cnt[t] : 0;
    if (t < BK) base[t] = excl;
    int node = bu * BK + t;
    if (t < BK && node < N) {
        offs[node] = lo + excl;
        float d = rsqrtf((float)(cnt[t] + 1));   // +1 self-loop
        dis[node] = d;
        dx[node]  = d * x[node];
    }
    if (bu == NB - 1 && t == 0) offs[N] = hi;
    __syncthreads();
    for (int k = lo + t; k < hi; k += 256) {
        unsigned en = stag[k];
        int p = atomicAdd(&base[en & (BK - 1)], 1);
        csr[lo + p] = (int)(en >> 7);
    }
}

// layer-1 scalar aggregation: thread per node on sorted CSR (self-loop analytic)
__global__ void k_agg1(const int* offs, const int* csr, const float* dx,
                       const float* dis, float* s1, int N) {
    int i = blockIdx.x * blockDim.x + threadIdx.x;
    if (i >= N) return;
    int b = offs[i], e = offs[i + 1];
    float acc = 0.f;
    int k = b;
    for (; k + 4 <= e; k += 4) {
        int s0 = csr[k], s1_ = csr[k + 1], s2 = csr[k + 2], s3 = csr[k + 3];
        float v0 = dx[s0], v1 = dx[s1_], v2 = dx[s2], v3 = dx[s3];
        acc += (v0 + v1) + (v2 + v3);
    }
    for (; k < e; ++k) acc += dx[csr[k]];
    s1[i] = dis[i] * (acc + dx[i]);
}

// hw1b[i] = bf16( dis[i] * (relu(s1[i]*Wg1 + bg1) @ Wg2) ), Wg2 in LDS
__global__ void __launch_bounds__(256) k_hw1(const float* s1, const float* dis,
                                             const float* Wg1, const float* bg1,
                                             const float* Wg2,
                                             __hip_bfloat16* hw1b, int N) {
    __shared__ float w2[64 * 64];
    __shared__ float h1l[4][64];
    int t = threadIdx.x;
    for (int k = t; k < 64 * 64; k += 256) w2[k] = Wg2[k];
    int nl = t >> 6, l = t & 63;
    int base = blockIdx.x * 16;
    for (int g = 0; g < 4; ++g) {
        int node = base + g * 4 + nl;
        float h1 = 0.f;
        if (node < N)
            h1 = fmaxf(fmaf(s1[node], Wg1[l], bg1[l]), 0.f);
        __syncthreads();
        h1l[nl][l] = h1;
        __syncthreads();
        if (node < N) {
            float acc = 0.f;
            const float* hr = h1l[nl];
            #pragma unroll
            for (int k = 0; k < 64; ++k) acc += hr[k] * w2[k * 64 + l];
            hw1b[node * 64 + l] = __float2bfloat16(dis[node] * acc);
        }
    }
}

// layer-2 aggregation: wave per dst node, lane = feature, register acc,
// 8 gathers in flight; dis[src] pre-folded into hw1b; self-loop analytic.
__global__ void __launch_bounds__(256) k_agg2(const int* offs, const int* csr,
                                              const __hip_bfloat16* hw1b,
                                              const float* dis, const float* bg2,
                                              const int* batch, float* pool, int N) {
    int i = (blockIdx.x * 256 + threadIdx.x) >> 6;  // node = global wave id
    int l = threadIdx.x & 63;
    if (i >= N) return;
    int b = offs[i], e = offs[i + 1];
    float acc = 0.f;
    int k = b;
    for (; k + 8 <= e; k += 8) {
        int s0 = csr[k], s1 = csr[k + 1], s2 = csr[k + 2], s3 = csr[k + 3];
        int s4 = csr[k + 4], s5 = csr[k + 5], s6 = csr[k + 6], s7 = csr[k + 7];
        float v0 = __bfloat162float(hw1b[s0 * 64 + l]);
        float v1 = __bfloat162float(hw1b[s1 * 64 + l]);
        float v2 = __bfloat162float(hw1b[s2 * 64 + l]);
        float v3 = __bfloat162float(hw1b[s3 * 64 + l]);
        float v4 = __bfloat162float(hw1b[s4 * 64 + l]);
        float v5 = __bfloat162float(hw1b[s5 * 64 + l]);
        float v6 = __bfloat162float(hw1b[s6 * 64 + l]);
        float v7 = __bfloat162float(hw1b[s7 * 64 + l]);
        acc += ((v0 + v1) + (v2 + v3)) + ((v4 + v5) + (v6 + v7));
    }
    for (; k < e; ++k) acc += __bfloat162float(hw1b[csr[k] * 64 + l]);
    acc += __bfloat162float(hw1b[i * 64 + l]);   // self-loop
    float h2 = fmaxf(fmaf(dis[i], acc, bg2[l]), 0.f);
    atomicAdd(&pool[batch[i] * 64 + l], h2);
}

// per-graph head: tabular MLP + mean pool + fusion MLP. 64 threads per graph.
__global__ void __launch_bounds__(64) k_head(const float* tabular,
        const float* Wt1, const float* bt1, const float* Wt2, const float* bt2,
        const float* Wf1, const float* bf1, const float* Wf2, const float* bf2,
        const float* pool, const int* batch, float* out, int TD, int N) {
    __shared__ float tl[128];
    __shared__ float t1[64];
    __shared__ float comb[128];
    __shared__ float f1[64];
    __shared__ float cnts;
    int g = blockIdx.x, l = threadIdx.x;
    if (l == 0) {
        int lo = 0, hi = N;
        while (lo < hi) { int m = (lo + hi) >> 1; if (batch[m] < g) lo = m + 1; else hi = m; }
        int lo2 = lo, hi2 = N;
        while (lo2 < hi2) { int m = (lo2 + hi2) >> 1; if (batch[m] <= g) lo2 = m + 1; else hi2 = m; }
        int c = lo2 - lo;
        cnts = (float)(c > 1 ? c : 1);
    }
    for (int k = l; k < TD; k += 64) tl[k] = tabular[g * TD + k];
    __syncthreads();
    float a = bt1[l];
    for (int k = 0; k < TD; ++k) a += tl[k] * Wt1[k * 64 + l];
    t1[l] = a > 0.f ? a : 0.f;
    __syncthreads();
    float b = bt2[l];
    #pragma unroll
    for (int k = 0; k < 64; ++k) b += t1[k] * Wt2[k * 64 + l];
    comb[l] = b;
    comb[64 + l] = pool[g * 64 + l] / cnts;
    __syncthreads();
    float f = bf1[l];
    for (int k = 0; k < 128; ++k) f += comb[k] * Wf1[k * 64 + l];
    f1[l] = f > 0.f ? f : 0.f;
    __syncthreads();
    if (l < 2) {
        float o = bf2[l];
        #pragma unroll
        for (int k = 0; k < 64; ++k) o += f1[k] * Wf2[k * 2 + l];
        out[g * 2 + l] = o;
    }
}

// ---------------- launcher ----------------

extern "C" void kernel_launch(void* const* d_in, const int* in_sizes, int n_in,
                              void* d_out, int out_size, void* d_ws, size_t ws_size,
                              hipStream_t stream) {
    const float* tabular = (const float*)d_in[0];
    const float* x       = (const float*)d_in[1];
    const int*   ei      = (const int*)d_in[2];
    const int*   batch   = (const int*)d_in[3];
    const float* Wt1 = (const float*)d_in[4];
    const float* bt1 = (const float*)d_in[5];
    const float* Wt2 = (const float*)d_in[6];
    const float* bt2 = (const float*)d_in[7];
    const float* Wg1 = (const float*)d_in[8];
    const float* bg1 = (const float*)d_in[9];
    const float* Wg2 = (const float*)d_in[10];
    const float* bg2 = (const float*)d_in[11];
    const float* Wf1 = (const float*)d_in[12];
    const float* bf1 = (const float*)d_in[13];
    const float* Wf2 = (const float*)d_in[14];
    const float* bf2 = (const float*)d_in[15];

    const int N  = in_sizes[1];
    const int E  = in_sizes[2] / 2;
    const int H  = in_sizes[5];             // 64
    const int TD = in_sizes[4] / H;         // 128
    const int B  = in_sizes[0] / TD;        // 1024
    const int NB = (N + BK - 1) / BK;       // 1563

    // workspace layout
    char* w = (char*)d_ws;
    size_t off = 0;
    auto alloc = [&](size_t bytes) -> void* {
        void* p = w + off;
        off = (off + bytes + 255) & ~(size_t)255;
        return p;
    };
    int*   bcnt = (int*)alloc((size_t)NBMAX * 4);
    int*   boff = (int*)alloc((size_t)(NBMAX + 1) * 4);
    int*   bcur = (int*)alloc((size_t)NBMAX * 4);
    int*   offs = (int*)alloc((size_t)(N + 1) * 4);
    float* dis  = (float*)alloc((size_t)N * 4);
    float* dx   = (float*)alloc((size_t)N * 4);
    float* s1   = (float*)alloc((size_t)N * 4);
    unsigned* stag = (unsigned*)alloc((size_t)E * 4);
    int*   csr  = (int*)alloc((size_t)E * 4);
    __hip_bfloat16* hw1b = (__hip_bfloat16*)alloc((size_t)N * 64 * 2);
    float* pool = (float*)alloc((size_t)B * 64 * 4);
    (void)ws_size;

    hipMemsetAsync(bcnt, 0, (size_t)NB * 4, stream);
    hipMemsetAsync(pool, 0, (size_t)B * 64 * 4, stream);

    k_bcount<<<512, 256, 0, stream>>>(ei + E, bcnt, E, NB);
    k_bscan<<<1, 256, 0, stream>>>(bcnt, boff, bcur, NB, E);
    k_bscatter<<<(E + EPB - 1) / EPB, 256, 0, stream>>>(ei, bcur, stag, E, NB);
    k_sort<<<NB, 256, 0, stream>>>(boff, stag, x, csr, offs, dis, dx, N, NB);
    k_agg1<<<(N + 255) / 256, 256, 0, stream>>>(offs, csr, dx, dis, s1, N);
    k_hw1<<<(N + 15) / 16, 256, 0, stream>>>(s1, dis, Wg1, bg1, Wg2, hw1b, N);
    k_agg2<<<(N + 3) / 4, 256, 0, stream>>>(offs, csr, hw1b, dis, bg2, batch, pool, N);
    k_head<<<B, 64, 0, stream>>>(tabular, Wt1, bt1, Wt2, bt2,
                                 Wf1, bf1, Wf2, bf2, pool, batch,
                                 (float*)d_out, TD, N);
}